// Round 7
// baseline (4323.725 us; speedup 1.0000x reference)
//
#include <hip/hip_runtime.h>
#include <hip/hip_bf16.h>

#define NB 8
#define CIN 3
#define HH 224
#define WW 224
#define OC 32
#define NH 8
#define HD 4
#define NHD 32   // NH*HD
#define C96 96
#define HWSZ (HH*WW)

// W2 = upd_w @ proj_w ; b2 = upd_w @ proj_b + upd_b   (1x1 conv composition)
__global__ void k_w2(const float* __restrict__ pw, const float* __restrict__ pb,
                     const float* __restrict__ uw, const float* __restrict__ ub,
                     float* __restrict__ W2, float* __restrict__ b2) {
    int c = threadIdx.x, o = threadIdx.y;  // 32x32
    float acc = 0.f;
    for (int m = 0; m < OC; ++m) acc = fmaf(uw[o*OC + m], pw[m*OC + c], acc);
    W2[o*OC + c] = acc;
    if (c == 0) {
        float bb = ub[o];
        for (int m = 0; m < OC; ++m) bb = fmaf(uw[o*OC + m], pb[m], bb);
        b2[o] = bb;
    }
}

// x (8,3,224,224) fp32 -> x1 (8,32,224,224) fp32, 3x3 pad1.
// OpenBLAS-sgemm emulation (im2col conv): sequential (c,kh,kw) K-loop,
// single accumulator, FMA, bias broadcast-added AFTER the sum.
__global__ void k_conv_in32(const float* __restrict__ x,
                            const float* __restrict__ w,
                            const float* __restrict__ bias,
                            float* __restrict__ x1) {
    int h = blockIdx.x, oc = blockIdx.y, b = blockIdx.z;
    __shared__ float wt[CIN*9];
    __shared__ float bs;
    if (threadIdx.x < CIN*9) wt[threadIdx.x] = w[oc*CIN*9 + threadIdx.x];
    if (threadIdx.x == 0) bs = bias[oc];
    __syncthreads();
    int wv = threadIdx.x;
    if (wv >= WW) return;
    float acc = 0.f;
    for (int c = 0; c < CIN; ++c)
        for (int kh = 0; kh < 3; ++kh) {
            int hh = h + kh - 1;
            if (hh < 0 || hh >= HH) continue;   // padded zeros: fmaf(0,w,acc)==acc, skip is exact
            const float* xr = x + ((size_t)(b*CIN + c)*HH + hh)*WW;
            const float* wr = &wt[c*9 + kh*3];
            if (wv > 0)     acc = fmaf(xr[wv-1], wr[0], acc);
                            acc = fmaf(xr[wv],   wr[1], acc);
            if (wv < WW-1)  acc = fmaf(xr[wv+1], wr[2], acc);
        }
    x1[((size_t)(b*OC + oc)*HH + h)*WW + wv] = __fadd_rn(acc, bs);
}

// per-batch: x1(b) fp32 -> q,k fp32 (planes n*8+{0,4}+d) and v fp32 (plane n*4+d)
// Same sgemm-emulation, no bias.
__global__ void k_conv_qkv32(const float* __restrict__ x1b,
                             const float* __restrict__ w,
                             float* __restrict__ qk,
                             float* __restrict__ vb) {
    int h = blockIdx.x, oc = blockIdx.y;
    __shared__ float wt[OC*9];
    for (int t = threadIdx.x; t < OC*9; t += blockDim.x)
        wt[t] = w[(size_t)oc*OC*9 + t];
    __syncthreads();
    int wv = threadIdx.x;
    if (wv >= WW) return;
    float acc = 0.f;
    for (int c = 0; c < OC; ++c) {
        const float* xb = x1b + ((size_t)c*HH)*WW;
        for (int kh = 0; kh < 3; ++kh) {
            int hh = h + kh - 1;
            if (hh < 0 || hh >= HH) continue;
            const float* xr = xb + (size_t)hh*WW;
            const float* wr = &wt[c*9 + kh*3];
            if (wv > 0)     acc = fmaf(xr[wv-1], wr[0], acc);
                            acc = fmaf(xr[wv],   wr[1], acc);
            if (wv < WW-1)  acc = fmaf(xr[wv+1], wr[2], acc);
        }
    }
    int n = oc / 12, rem = oc % 12;
    int r = rem >> 2, d = rem & 3;
    if (r < 2)
        qk[((size_t)(n*8 + r*4 + d)*HH + h)*WW + wv] = acc;
    else
        vb[((size_t)(n*4 + d)*HH + h)*WW + wv] = acc;
}

// per-batch, per (nd,i): dot emulates np.einsum float32 SSE1 path:
//   4-lane accumulator (lane l gets w ≡ l mod 4), separate mul+add (NO fma),
//   final reduce (s0+s1)+(s2+s3). logit = 0.5f*dot (exact) + gumbel (one rounded add).
// argmax first-index -> idx, one-hot att
__global__ void k_attn32(const float* __restrict__ qk,
                         const float* __restrict__ gum,   // + b*NH*HD*HH*HH
                         float* __restrict__ att,         // + b*NH*HD*HH*HH
                         int* __restrict__ idxout) {      // + b*NHD*HH
    int i = blockIdx.x, nd = blockIdx.y;
    int n = nd >> 2, d = nd & 3;
    const float* qr = qk + ((size_t)(n*8 + d)*HH + i)*WW;
    const float* kb = qk + ((size_t)(n*8 + 4 + d)*HH)*WW;
    __shared__ float qs[WW];
    __shared__ float vals[256];
    __shared__ int   inds[256];
    __shared__ int   win;
    int t = threadIdx.x;
    if (t < WW) qs[t] = qr[t];
    __syncthreads();
    float v = -INFINITY;
    if (t < WW) {
        const float* kr = kb + (size_t)t*WW;
        float s0 = 0.f, s1 = 0.f, s2 = 0.f, s3 = 0.f;
        for (int w = 0; w < WW; w += 4) {
            s0 = __fadd_rn(s0, __fmul_rn(qs[w+0], kr[w+0]));
            s1 = __fadd_rn(s1, __fmul_rn(qs[w+1], kr[w+1]));
            s2 = __fadd_rn(s2, __fmul_rn(qs[w+2], kr[w+2]));
            s3 = __fadd_rn(s3, __fmul_rn(qs[w+3], kr[w+3]));
        }
        float dot = __fadd_rn(__fadd_rn(s0, s1), __fadd_rn(s2, s3));
        v = __fadd_rn(__fmul_rn(0.5f, dot), gum[((size_t)nd*HH + i)*HH + t]);
    }
    vals[t] = v; inds[t] = t;
    __syncthreads();
    for (int s = 128; s > 0; s >>= 1) {
        if (t < s) {
            float v2 = vals[t+s]; int i2 = inds[t+s];
            if (v2 > vals[t] || (v2 == vals[t] && i2 < inds[t])) { vals[t] = v2; inds[t] = i2; }
        }
        __syncthreads();
    }
    if (t == 0) { win = inds[0]; idxout[nd*HH + i] = win; }
    __syncthreads();
    if (t < WW)
        att[((size_t)nd*HH + i)*HH + t] = (t == win) ? 1.f : 0.f;
}

// recompute A2 = W2*gather(v) + b2 per pixel, accumulate per-channel sum/sumsq
__global__ void k_gather_stats(const float* __restrict__ vbuf,
                               const int* __restrict__ idx,
                               const float* __restrict__ W2g,
                               const float* __restrict__ b2g,
                               float* __restrict__ sums, float* __restrict__ sumsq) {
    int i = blockIdx.x, b = blockIdx.y;
    __shared__ float w2s[OC*OC];
    __shared__ float b2s[OC];
    __shared__ int   id[OC];
    __shared__ float ssum[OC], ssq[OC];
    for (int t = threadIdx.x; t < OC*OC; t += blockDim.x) w2s[t] = W2g[t];
    if (threadIdx.x < OC) {
        b2s[threadIdx.x]  = b2g[threadIdx.x];
        id[threadIdx.x]   = idx[(b*NHD + threadIdx.x)*HH + i];
        ssum[threadIdx.x] = 0.f;
        ssq[threadIdx.x]  = 0.f;
    }
    __syncthreads();
    int wv = threadIdx.x;
    bool act = wv < WW;
    float vals[OC];
    if (act)
        for (int c = 0; c < OC; ++c)
            vals[c] = vbuf[((size_t)(b*OC + c)*HH + id[c])*WW + wv];
    for (int oc = 0; oc < OC; ++oc) {
        float a = 0.f, a2 = 0.f;
        if (act) {
            a = b2s[oc];
            for (int c = 0; c < OC; ++c) a = fmaf(w2s[oc*OC + c], vals[c], a);
            a2 = a*a;
        }
        for (int off = 32; off > 0; off >>= 1) {
            a  += __shfl_down(a,  off, 64);
            a2 += __shfl_down(a2, off, 64);
        }
        if ((threadIdx.x & 63) == 0) {
            atomicAdd(&ssum[oc], a);
            atomicAdd(&ssq[oc],  a2);
        }
    }
    __syncthreads();
    if (threadIdx.x < OC) {
        atomicAdd(&sums[threadIdx.x],  ssum[threadIdx.x]);
        atomicAdd(&sumsq[threadIdx.x], ssq[threadIdx.x]);
    }
}

// recompute A2, BN + SiLU + residual, write fp32 out
__global__ void k_final(const float* __restrict__ vbuf,
                        const int* __restrict__ idx,
                        const float* __restrict__ W2g,
                        const float* __restrict__ b2g,
                        const float* __restrict__ x1,
                        const float* __restrict__ sums, const float* __restrict__ sumsq,
                        const float* __restrict__ gamma, const float* __restrict__ beta,
                        float* __restrict__ out) {
    int i = blockIdx.x, b = blockIdx.y;
    __shared__ float w2s[OC*OC];
    __shared__ float b2s[OC];
    __shared__ int   id[OC];
    __shared__ float mean_s[OC], inv_s[OC], g_s[OC], be_s[OC];
    for (int t = threadIdx.x; t < OC*OC; t += blockDim.x) w2s[t] = W2g[t];
    if (threadIdx.x < OC) {
        int oc = threadIdx.x;
        b2s[oc] = b2g[oc];
        id[oc]  = idx[(b*NHD + oc)*HH + i];
        const float N = (float)(NB*HH*WW);
        float mean = sums[oc]/N;
        float var  = sumsq[oc]/N - mean*mean;
        mean_s[oc] = mean;
        inv_s[oc]  = rsqrtf(var + 1e-5f);
        g_s[oc]    = gamma[oc];
        be_s[oc]   = beta[oc];
    }
    __syncthreads();
    int wv = threadIdx.x;
    if (wv >= WW) return;
    float vals[OC];
    for (int c = 0; c < OC; ++c)
        vals[c] = vbuf[((size_t)(b*OC + c)*HH + id[c])*WW + wv];
    for (int oc = 0; oc < OC; ++oc) {
        float a = b2s[oc];
        for (int c = 0; c < OC; ++c) a = fmaf(w2s[oc*OC + c], vals[c], a);
        float an = (a - mean_s[oc])*inv_s[oc]*g_s[oc] + be_s[oc];
        float sw = an / (1.f + __expf(-an));
        size_t o = ((size_t)(b*OC + oc)*HH + i)*WW + wv;
        out[o] = sw + x1[o];
    }
}

extern "C" void kernel_launch(void* const* d_in, const int* in_sizes, int n_in,
                              void* d_out, int out_size, void* d_ws, size_t ws_size,
                              hipStream_t stream) {
    const float* x      = (const float*)d_in[0];
    const float* gumbel = (const float*)d_in[1];
    const float* in_w   = (const float*)d_in[2];
    const float* in_b   = (const float*)d_in[3];
    const float* qkv_w  = (const float*)d_in[4];
    const float* proj_w = (const float*)d_in[5];
    const float* proj_b = (const float*)d_in[6];
    const float* upd_w  = (const float*)d_in[7];
    const float* upd_b  = (const float*)d_in[8];
    const float* bng    = (const float*)d_in[9];
    const float* bnb    = (const float*)d_in[10];

    float* out = (float*)d_out;
    float* att = out + (size_t)NB*OC*HWSZ;

    // ws layout, total ~116 MB
    float* x1   = (float*)d_ws;                      // 12,845,056 f (51.4 MB)
    float* qkb  = x1 + (size_t)NB*OC*HWSZ;           //  3,211,264 f (12.8 MB, per-batch)
    float* vbuf = qkb + (size_t)64*HWSZ;             // 12,845,056 f (51.4 MB)
    float* W2   = vbuf + (size_t)NB*OC*HWSZ;         // 1024
    float* b2   = W2 + OC*OC;                        // 32
    float* sums = b2 + OC;                           // 32
    float* sumsq= sums + OC;                         // 32
    int*   idx  = (int*)(sumsq + OC);                // 57,344 ints

    hipMemsetAsync(sums, 0, 2*OC*sizeof(float), stream);

    k_w2       <<<1, dim3(OC, OC), 0, stream>>>(proj_w, proj_b, upd_w, upd_b, W2, b2);
    k_conv_in32<<<dim3(HH, OC, NB), 256, 0, stream>>>(x, in_w, in_b, x1);

    for (int b = 0; b < NB; ++b) {
        k_conv_qkv32<<<dim3(HH, C96), 256, 0, stream>>>(
            x1 + (size_t)b*OC*HWSZ, qkv_w, qkb, vbuf + (size_t)b*OC*HWSZ);
        k_attn32<<<dim3(HH, NHD), 256, 0, stream>>>(
            qkb,
            gumbel + (size_t)b*NH*HD*HH*HH,
            att    + (size_t)b*NH*HD*HH*HH,
            idx    + (size_t)b*NHD*HH);
    }

    k_gather_stats<<<dim3(HH, NB), 256, 0, stream>>>(vbuf, idx, W2, b2, sums, sumsq);
    k_final       <<<dim3(HH, NB), 256, 0, stream>>>(vbuf, idx, W2, b2, x1, sums, sumsq, bng, bnb, out);
}

// Round 8
// 2380.110 us; speedup vs baseline: 1.8166x; 1.8166x over previous
//
#include <hip/hip_runtime.h>
#include <hip/hip_bf16.h>

#define NB 8
#define CIN 3
#define HH 224
#define WW 224
#define OC 32
#define NH 8
#define HD 4
#define NHD 32   // NH*HD
#define C96 96
#define HWSZ (HH*WW)

#define HT 4     // h rows per block (conv_qkv tile)
#define OCT 8    // output channels per block

// W2 = upd_w @ proj_w ; b2 = upd_w @ proj_b + upd_b   (1x1 conv composition)
__global__ void k_w2(const float* __restrict__ pw, const float* __restrict__ pb,
                     const float* __restrict__ uw, const float* __restrict__ ub,
                     float* __restrict__ W2, float* __restrict__ b2) {
    int c = threadIdx.x, o = threadIdx.y;  // 32x32
    float acc = 0.f;
    for (int m = 0; m < OC; ++m) acc = fmaf(uw[o*OC + m], pw[m*OC + c], acc);
    W2[o*OC + c] = acc;
    if (c == 0) {
        float bb = ub[o];
        for (int m = 0; m < OC; ++m) bb = fmaf(uw[o*OC + m], pb[m], bb);
        b2[o] = bb;
    }
}

// x (8,3,224,224) fp32 -> x1 (8,32,224,224) fp32, 3x3 pad1.
// OpenBLAS-sgemm emulation: sequential (c,kh,kw) K-loop, single FMA chain,
// bias broadcast-added AFTER the sum.
__global__ void k_conv_in32(const float* __restrict__ x,
                            const float* __restrict__ w,
                            const float* __restrict__ bias,
                            float* __restrict__ x1) {
    int h = blockIdx.x, oc = blockIdx.y, b = blockIdx.z;
    __shared__ float wt[CIN*9];
    __shared__ float bs;
    if (threadIdx.x < CIN*9) wt[threadIdx.x] = w[oc*CIN*9 + threadIdx.x];
    if (threadIdx.x == 0) bs = bias[oc];
    __syncthreads();
    int wv = threadIdx.x;
    if (wv >= WW) return;
    float acc = 0.f;
    for (int c = 0; c < CIN; ++c)
        for (int kh = 0; kh < 3; ++kh) {
            int hh = h + kh - 1;
            if (hh < 0 || hh >= HH) continue;   // padded zeros: exact skip
            const float* xr = x + ((size_t)(b*CIN + c)*HH + hh)*WW;
            const float* wr = &wt[c*9 + kh*3];
            if (wv > 0)     acc = fmaf(xr[wv-1], wr[0], acc);
                            acc = fmaf(xr[wv],   wr[1], acc);
            if (wv < WW-1)  acc = fmaf(xr[wv+1], wr[2], acc);
        }
    x1[((size_t)(b*OC + oc)*HH + h)*WW + wv] = __fadd_rn(acc, bs);
}

// Tiled qkv conv: block = HT h-rows x OCT ocs. Per channel c: stage (HT+2) input
// rows (zero halo) into LDS, hoist 3x(HT+2) window to regs, reuse across OCT ocs.
// Per-output accumulation order identical to r7: c asc -> kh -> kw, single fmaf chain.
__global__ __launch_bounds__(256) void k_conv_qkv_tile(const float* __restrict__ x1b,
                                                       const float* __restrict__ w,
                                                       float* __restrict__ qk,
                                                       float* __restrict__ vb) {
    int h0 = blockIdx.x * HT;          // 56
    int og = blockIdx.y * OCT;         // 12
    __shared__ float xs[HT+2][226];
    int t = threadIdx.x;
    int wv = t;
    float acc[HT][OCT];
    #pragma unroll
    for (int a = 0; a < HT; ++a)
        #pragma unroll
        for (int o = 0; o < OCT; ++o) acc[a][o] = 0.f;

    for (int c = 0; c < OC; ++c) {
        __syncthreads();   // protect previous iteration's LDS reads
        for (int e = t; e < (HT+2)*226; e += 256) {
            int r = e / 226, col = e % 226;
            int gh = h0 - 1 + r;
            float vvv = 0.f;
            if (gh >= 0 && gh < HH && col > 0 && col < 225)
                vvv = x1b[((size_t)c*HH + gh)*WW + (col-1)];
            xs[r][col] = vvv;
        }
        __syncthreads();
        if (wv < WW) {
            float xv[HT+2][3];
            #pragma unroll
            for (int r = 0; r < HT+2; ++r)
                #pragma unroll
                for (int j = 0; j < 3; ++j)
                    xv[r][j] = xs[r][wv + j];
            #pragma unroll
            for (int o = 0; o < OCT; ++o) {
                const float* wr = w + ((size_t)(og + o)*OC + c)*9;
                #pragma unroll
                for (int kh = 0; kh < 3; ++kh)
                    #pragma unroll
                    for (int kw = 0; kw < 3; ++kw) {
                        float wgt = wr[kh*3 + kw];
                        #pragma unroll
                        for (int hy = 0; hy < HT; ++hy)
                            acc[hy][o] = fmaf(xv[hy+kh][kw], wgt, acc[hy][o]);
                    }
            }
        }
    }
    if (wv < WW) {
        #pragma unroll
        for (int o = 0; o < OCT; ++o) {
            int oc = og + o;
            int n = oc / 12, rem = oc % 12;
            int r = rem >> 2, d = rem & 3;
            #pragma unroll
            for (int hy = 0; hy < HT; ++hy) {
                int h = h0 + hy;
                if (r < 2)
                    qk[((size_t)(n*8 + r*4 + d)*HH + h)*WW + wv] = acc[hy][o];
                else
                    vb[((size_t)(n*4 + d)*HH + h)*WW + wv] = acc[hy][o];
            }
        }
    }
}

// per-batch, per (nd,i): dot emulates np.einsum float32 SSE1 path:
//   4-lane accumulator, separate mul+add (NO fma), final (s0+s1)+(s2+s3).
// logit = 0.5f*dot (exact) + gumbel (one rounded add). argmax -> idx, one-hot att.
__global__ void k_attn32(const float* __restrict__ qk,
                         const float* __restrict__ gum,   // + b*NH*HD*HH*HH
                         float* __restrict__ att,         // + b*NH*HD*HH*HH
                         int* __restrict__ idxout) {      // + b*NHD*HH
    int i = blockIdx.x, nd = blockIdx.y;
    int n = nd >> 2, d = nd & 3;
    const float* qr = qk + ((size_t)(n*8 + d)*HH + i)*WW;
    const float* kb = qk + ((size_t)(n*8 + 4 + d)*HH)*WW;
    __shared__ float qs[WW];
    __shared__ float vals[256];
    __shared__ int   inds[256];
    __shared__ int   win;
    int t = threadIdx.x;
    if (t < WW) qs[t] = qr[t];
    __syncthreads();
    float v = -INFINITY;
    if (t < WW) {
        const float* kr = kb + (size_t)t*WW;
        float s0 = 0.f, s1 = 0.f, s2 = 0.f, s3 = 0.f;
        for (int w = 0; w < WW; w += 4) {
            s0 = __fadd_rn(s0, __fmul_rn(qs[w+0], kr[w+0]));
            s1 = __fadd_rn(s1, __fmul_rn(qs[w+1], kr[w+1]));
            s2 = __fadd_rn(s2, __fmul_rn(qs[w+2], kr[w+2]));
            s3 = __fadd_rn(s3, __fmul_rn(qs[w+3], kr[w+3]));
        }
        float dot = __fadd_rn(__fadd_rn(s0, s1), __fadd_rn(s2, s3));
        v = __fadd_rn(__fmul_rn(0.5f, dot), gum[((size_t)nd*HH + i)*HH + t]);
    }
    vals[t] = v; inds[t] = t;
    __syncthreads();
    for (int s = 128; s > 0; s >>= 1) {
        if (t < s) {
            float v2 = vals[t+s]; int i2 = inds[t+s];
            if (v2 > vals[t] || (v2 == vals[t] && i2 < inds[t])) { vals[t] = v2; inds[t] = i2; }
        }
        __syncthreads();
    }
    if (t == 0) { win = inds[0]; idxout[nd*HH + i] = win; }
    __syncthreads();
    if (t < WW)
        att[((size_t)nd*HH + i)*HH + t] = (t == win) ? 1.f : 0.f;
}

// recompute A2 = W2*gather(v) + b2 per pixel, accumulate per-channel sum/sumsq
__global__ void k_gather_stats(const float* __restrict__ vbuf,
                               const int* __restrict__ idx,
                               const float* __restrict__ W2g,
                               const float* __restrict__ b2g,
                               float* __restrict__ sums, float* __restrict__ sumsq) {
    int i = blockIdx.x, b = blockIdx.y;
    __shared__ float w2s[OC*OC];
    __shared__ float b2s[OC];
    __shared__ int   id[OC];
    __shared__ float ssum[OC], ssq[OC];
    for (int t = threadIdx.x; t < OC*OC; t += blockDim.x) w2s[t] = W2g[t];
    if (threadIdx.x < OC) {
        b2s[threadIdx.x]  = b2g[threadIdx.x];
        id[threadIdx.x]   = idx[(b*NHD + threadIdx.x)*HH + i];
        ssum[threadIdx.x] = 0.f;
        ssq[threadIdx.x]  = 0.f;
    }
    __syncthreads();
    int wv = threadIdx.x;
    bool act = wv < WW;
    float vals[OC];
    if (act)
        for (int c = 0; c < OC; ++c)
            vals[c] = vbuf[((size_t)(b*OC + c)*HH + id[c])*WW + wv];
    for (int oc = 0; oc < OC; ++oc) {
        float a = 0.f, a2 = 0.f;
        if (act) {
            a = b2s[oc];
            for (int c = 0; c < OC; ++c) a = fmaf(w2s[oc*OC + c], vals[c], a);
            a2 = a*a;
        }
        for (int off = 32; off > 0; off >>= 1) {
            a  += __shfl_down(a,  off, 64);
            a2 += __shfl_down(a2, off, 64);
        }
        if ((threadIdx.x & 63) == 0) {
            atomicAdd(&ssum[oc], a);
            atomicAdd(&ssq[oc],  a2);
        }
    }
    __syncthreads();
    if (threadIdx.x < OC) {
        atomicAdd(&sums[threadIdx.x],  ssum[threadIdx.x]);
        atomicAdd(&sumsq[threadIdx.x], ssq[threadIdx.x]);
    }
}

// recompute A2, BN + SiLU + residual, write fp32 out
__global__ void k_final(const float* __restrict__ vbuf,
                        const int* __restrict__ idx,
                        const float* __restrict__ W2g,
                        const float* __restrict__ b2g,
                        const float* __restrict__ x1,
                        const float* __restrict__ sums, const float* __restrict__ sumsq,
                        const float* __restrict__ gamma, const float* __restrict__ beta,
                        float* __restrict__ out) {
    int i = blockIdx.x, b = blockIdx.y;
    __shared__ float w2s[OC*OC];
    __shared__ float b2s[OC];
    __shared__ int   id[OC];
    __shared__ float mean_s[OC], inv_s[OC], g_s[OC], be_s[OC];
    for (int t = threadIdx.x; t < OC*OC; t += blockDim.x) w2s[t] = W2g[t];
    if (threadIdx.x < OC) {
        int oc = threadIdx.x;
        b2s[oc] = b2g[oc];
        id[oc]  = idx[(b*NHD + oc)*HH + i];
        const float N = (float)(NB*HH*WW);
        float mean = sums[oc]/N;
        float var  = sumsq[oc]/N - mean*mean;
        mean_s[oc] = mean;
        inv_s[oc]  = rsqrtf(var + 1e-5f);
        g_s[oc]    = gamma[oc];
        be_s[oc]   = beta[oc];
    }
    __syncthreads();
    int wv = threadIdx.x;
    if (wv >= WW) return;
    float vals[OC];
    for (int c = 0; c < OC; ++c)
        vals[c] = vbuf[((size_t)(b*OC + c)*HH + id[c])*WW + wv];
    for (int oc = 0; oc < OC; ++oc) {
        float a = b2s[oc];
        for (int c = 0; c < OC; ++c) a = fmaf(w2s[oc*OC + c], vals[c], a);
        float an = (a - mean_s[oc])*inv_s[oc]*g_s[oc] + be_s[oc];
        float sw = an / (1.f + __expf(-an));
        size_t o = ((size_t)(b*OC + oc)*HH + i)*WW + wv;
        out[o] = sw + x1[o];
    }
}

extern "C" void kernel_launch(void* const* d_in, const int* in_sizes, int n_in,
                              void* d_out, int out_size, void* d_ws, size_t ws_size,
                              hipStream_t stream) {
    const float* x      = (const float*)d_in[0];
    const float* gumbel = (const float*)d_in[1];
    const float* in_w   = (const float*)d_in[2];
    const float* in_b   = (const float*)d_in[3];
    const float* qkv_w  = (const float*)d_in[4];
    const float* proj_w = (const float*)d_in[5];
    const float* proj_b = (const float*)d_in[6];
    const float* upd_w  = (const float*)d_in[7];
    const float* upd_b  = (const float*)d_in[8];
    const float* bng    = (const float*)d_in[9];
    const float* bnb    = (const float*)d_in[10];

    float* out = (float*)d_out;
    float* att = out + (size_t)NB*OC*HWSZ;

    // ws layout, total ~116 MB
    float* x1   = (float*)d_ws;                      // 12,845,056 f (51.4 MB)
    float* qkb  = x1 + (size_t)NB*OC*HWSZ;           //  3,211,264 f (12.8 MB, per-batch)
    float* vbuf = qkb + (size_t)64*HWSZ;             // 12,845,056 f (51.4 MB)
    float* W2   = vbuf + (size_t)NB*OC*HWSZ;         // 1024
    float* b2   = W2 + OC*OC;                        // 32
    float* sums = b2 + OC;                           // 32
    float* sumsq= sums + OC;                         // 32
    int*   idx  = (int*)(sumsq + OC);                // 57,344 ints

    hipMemsetAsync(sums, 0, 2*OC*sizeof(float), stream);

    k_w2       <<<1, dim3(OC, OC), 0, stream>>>(proj_w, proj_b, upd_w, upd_b, W2, b2);
    k_conv_in32<<<dim3(HH, OC, NB), 256, 0, stream>>>(x, in_w, in_b, x1);

    for (int b = 0; b < NB; ++b) {
        k_conv_qkv_tile<<<dim3(HH/HT, C96/OCT), 256, 0, stream>>>(
            x1 + (size_t)b*OC*HWSZ, qkv_w, qkb, vbuf + (size_t)b*OC*HWSZ);
        k_attn32<<<dim3(HH, NHD), 256, 0, stream>>>(
            qkb,
            gumbel + (size_t)b*NH*HD*HH*HH,
            att    + (size_t)b*NH*HD*HH*HH,
            idx    + (size_t)b*NHD*HH);
    }

    k_gather_stats<<<dim3(HH, NB), 256, 0, stream>>>(vbuf, idx, W2, b2, sums, sumsq);
    k_final       <<<dim3(HH, NB), 256, 0, stream>>>(vbuf, idx, W2, b2, x1, sums, sumsq, bng, bnb, out);
}

// Round 9
// 1378.157 us; speedup vs baseline: 3.1373x; 1.7270x over previous
//
#include <hip/hip_runtime.h>
#include <hip/hip_bf16.h>

#define NB 8
#define CIN 3
#define HH 224
#define WW 224
#define OC 32
#define NH 8
#define HD 4
#define NHD 32   // NH*HD
#define C96 96
#define HWSZ (HH*WW)

#define HT 4     // h rows per block (conv_qkv tile)
#define OCT 8    // output channels per block

// W2 = upd_w @ proj_w ; b2 = upd_w @ proj_b + upd_b   (1x1 conv composition)
__global__ void k_w2(const float* __restrict__ pw, const float* __restrict__ pb,
                     const float* __restrict__ uw, const float* __restrict__ ub,
                     float* __restrict__ W2, float* __restrict__ b2) {
    int c = threadIdx.x, o = threadIdx.y;  // 32x32
    float acc = 0.f;
    for (int m = 0; m < OC; ++m) acc = fmaf(uw[o*OC + m], pw[m*OC + c], acc);
    W2[o*OC + c] = acc;
    if (c == 0) {
        float bb = ub[o];
        for (int m = 0; m < OC; ++m) bb = fmaf(uw[o*OC + m], pb[m], bb);
        b2[o] = bb;
    }
}

// x (8,3,224,224) fp32 -> x1 (8,32,224,224) fp32, 3x3 pad1.
// OpenBLAS-sgemm emulation: sequential (c,kh,kw) K-loop, single FMA chain,
// bias broadcast-added AFTER the sum.
__global__ void k_conv_in32(const float* __restrict__ x,
                            const float* __restrict__ w,
                            const float* __restrict__ bias,
                            float* __restrict__ x1) {
    int h = blockIdx.x, oc = blockIdx.y, b = blockIdx.z;
    __shared__ float wt[CIN*9];
    __shared__ float bs;
    if (threadIdx.x < CIN*9) wt[threadIdx.x] = w[oc*CIN*9 + threadIdx.x];
    if (threadIdx.x == 0) bs = bias[oc];
    __syncthreads();
    int wv = threadIdx.x;
    if (wv >= WW) return;
    float acc = 0.f;
    for (int c = 0; c < CIN; ++c)
        for (int kh = 0; kh < 3; ++kh) {
            int hh = h + kh - 1;
            if (hh < 0 || hh >= HH) continue;   // padded zeros: exact skip
            const float* xr = x + ((size_t)(b*CIN + c)*HH + hh)*WW;
            const float* wr = &wt[c*9 + kh*3];
            if (wv > 0)     acc = fmaf(xr[wv-1], wr[0], acc);
                            acc = fmaf(xr[wv],   wr[1], acc);
            if (wv < WW-1)  acc = fmaf(xr[wv+1], wr[2], acc);
        }
    x1[((size_t)(b*OC + oc)*HH + h)*WW + wv] = __fadd_rn(acc, bs);
}

// Tiled qkv conv: block = HT h-rows x OCT ocs. Per channel c: stage (HT+2) input
// rows (zero halo) into LDS, hoist 3x(HT+2) window to regs, reuse across OCT ocs.
// Per-output accumulation order identical to r7: c asc -> kh -> kw, single fmaf chain.
__global__ __launch_bounds__(256) void k_conv_qkv_tile(const float* __restrict__ x1b,
                                                       const float* __restrict__ w,
                                                       float* __restrict__ qk,
                                                       float* __restrict__ vb) {
    int h0 = blockIdx.x * HT;          // 56
    int og = blockIdx.y * OCT;         // 12
    __shared__ float xs[HT+2][226];
    int t = threadIdx.x;
    int wv = t;
    float acc[HT][OCT];
    #pragma unroll
    for (int a = 0; a < HT; ++a)
        #pragma unroll
        for (int o = 0; o < OCT; ++o) acc[a][o] = 0.f;

    for (int c = 0; c < OC; ++c) {
        __syncthreads();   // protect previous iteration's LDS reads
        for (int e = t; e < (HT+2)*226; e += 256) {
            int r = e / 226, col = e % 226;
            int gh = h0 - 1 + r;
            float vvv = 0.f;
            if (gh >= 0 && gh < HH && col > 0 && col < 225)
                vvv = x1b[((size_t)c*HH + gh)*WW + (col-1)];
            xs[r][col] = vvv;
        }
        __syncthreads();
        if (wv < WW) {
            float xv[HT+2][3];
            #pragma unroll
            for (int r = 0; r < HT+2; ++r)
                #pragma unroll
                for (int j = 0; j < 3; ++j)
                    xv[r][j] = xs[r][wv + j];
            #pragma unroll
            for (int o = 0; o < OCT; ++o) {
                const float* wr = w + ((size_t)(og + o)*OC + c)*9;
                #pragma unroll
                for (int kh = 0; kh < 3; ++kh)
                    #pragma unroll
                    for (int kw = 0; kw < 3; ++kw) {
                        float wgt = wr[kh*3 + kw];
                        #pragma unroll
                        for (int hy = 0; hy < HT; ++hy)
                            acc[hy][o] = fmaf(xv[hy+kh][kw], wgt, acc[hy][o]);
                    }
            }
        }
    }
    if (wv < WW) {
        #pragma unroll
        for (int o = 0; o < OCT; ++o) {
            int oc = og + o;
            int n = oc / 12, rem = oc % 12;
            int r = rem >> 2, d = rem & 3;
            #pragma unroll
            for (int hy = 0; hy < HT; ++hy) {
                int h = h0 + hy;
                if (r < 2)
                    qk[((size_t)(n*8 + r*4 + d)*HH + h)*WW + wv] = acc[hy][o];
                else
                    vb[((size_t)(n*4 + d)*HH + h)*WW + wv] = acc[hy][o];
            }
        }
    }
}

// attention: block = (8 i-rows, nd). Thread t owns j=t, computes dots for all 8
// i-rows (k-row read once as float4, q broadcast from LDS). Dot semantics frozen:
// np.einsum SSE1 emulation — 4 separate no-fma lanes over ascending w, reduce
// (s0+s1)+(s2+s3); 0.5f* exact; gumbel added last. Argmax: ascending-j strict >,
// cross-lane tie-break to smaller j. Bit-identical to the r7 kernel.
__global__ __launch_bounds__(256) void k_attn_ri(const float* __restrict__ qk,
                                                 const float* __restrict__ gum,   // + b*NH*HD*HH*HH
                                                 float* __restrict__ att,         // + b*NH*HD*HH*HH
                                                 int* __restrict__ idxout) {      // + b*NHD*HH
    int i0 = blockIdx.x * 8;
    int nd = blockIdx.y;
    int n = nd >> 2, d = nd & 3;
    const float* qb = qk + ((size_t)(n*8 + d)*HH + i0)*WW;
    const float* kb = qk + ((size_t)(n*8 + 4 + d)*HH)*WW;
    __shared__ __align__(16) float qs[8][WW];
    __shared__ float vals[8][256];
    __shared__ int   win_s[8];
    int t = threadIdx.x;
    for (int f = t; f < 8*(WW/4); f += 256) {         // 448 float4
        int r = f / (WW/4), p = (f % (WW/4))*4;
        *(float4*)(&qs[r][p]) = *(const float4*)(qb + (size_t)r*WW + p);
    }
    __syncthreads();
    if (t < WW) {
        const float* kr = kb + (size_t)t*WW;
        float s0[8], s1[8], s2[8], s3[8];
        #pragma unroll
        for (int ii = 0; ii < 8; ++ii) { s0[ii]=0.f; s1[ii]=0.f; s2[ii]=0.f; s3[ii]=0.f; }
        for (int w = 0; w < WW; w += 4) {
            float4 kc = *(const float4*)(kr + w);
            #pragma unroll
            for (int ii = 0; ii < 8; ++ii) {
                float4 qc = *(const float4*)(&qs[ii][w]);
                s0[ii] = __fadd_rn(s0[ii], __fmul_rn(qc.x, kc.x));
                s1[ii] = __fadd_rn(s1[ii], __fmul_rn(qc.y, kc.y));
                s2[ii] = __fadd_rn(s2[ii], __fmul_rn(qc.z, kc.z));
                s3[ii] = __fadd_rn(s3[ii], __fmul_rn(qc.w, kc.w));
            }
        }
        #pragma unroll
        for (int ii = 0; ii < 8; ++ii) {
            float dot = __fadd_rn(__fadd_rn(s0[ii], s1[ii]), __fadd_rn(s2[ii], s3[ii]));
            vals[ii][t] = __fadd_rn(__fmul_rn(0.5f, dot),
                                    gum[((size_t)nd*HH + (i0 + ii))*HH + t]);
        }
    } else {
        #pragma unroll
        for (int ii = 0; ii < 8; ++ii) vals[ii][t] = -INFINITY;
    }
    __syncthreads();
    int ii = t >> 5, jj = t & 31;
    float best = -INFINITY; int bj = 0x7fffffff;
    for (int j = jj; j < 256; j += 32) {              // ascending j: strict > keeps first
        float v = vals[ii][j];
        if (v > best) { best = v; bj = j; }
    }
    for (int off = 16; off > 0; off >>= 1) {
        float v2 = __shfl_down(best, off, 32);
        int   j2 = __shfl_down(bj,   off, 32);
        if (v2 > best || (v2 == best && j2 < bj)) { best = v2; bj = j2; }
    }
    if (jj == 0) { win_s[ii] = bj; idxout[nd*HH + i0 + ii] = bj; }
    __syncthreads();
    for (int e = t; e < 8*WW; e += 256) {
        int r = e / WW, j = e - r*WW;
        att[((size_t)nd*HH + (i0 + r))*HH + j] = (j == win_s[r]) ? 1.f : 0.f;
    }
}

// recompute A2 = W2*gather(v) + b2 per pixel, accumulate per-channel sum/sumsq
__global__ void k_gather_stats(const float* __restrict__ vbuf,
                               const int* __restrict__ idx,
                               const float* __restrict__ W2g,
                               const float* __restrict__ b2g,
                               float* __restrict__ sums, float* __restrict__ sumsq) {
    int i = blockIdx.x, b = blockIdx.y;
    __shared__ float w2s[OC*OC];
    __shared__ float b2s[OC];
    __shared__ int   id[OC];
    __shared__ float ssum[OC], ssq[OC];
    for (int t = threadIdx.x; t < OC*OC; t += blockDim.x) w2s[t] = W2g[t];
    if (threadIdx.x < OC) {
        b2s[threadIdx.x]  = b2g[threadIdx.x];
        id[threadIdx.x]   = idx[(b*NHD + threadIdx.x)*HH + i];
        ssum[threadIdx.x] = 0.f;
        ssq[threadIdx.x]  = 0.f;
    }
    __syncthreads();
    int wv = threadIdx.x;
    bool act = wv < WW;
    float vals[OC];
    if (act)
        for (int c = 0; c < OC; ++c)
            vals[c] = vbuf[((size_t)(b*OC + c)*HH + id[c])*WW + wv];
    for (int oc = 0; oc < OC; ++oc) {
        float a = 0.f, a2 = 0.f;
        if (act) {
            a = b2s[oc];
            for (int c = 0; c < OC; ++c) a = fmaf(w2s[oc*OC + c], vals[c], a);
            a2 = a*a;
        }
        for (int off = 32; off > 0; off >>= 1) {
            a  += __shfl_down(a,  off, 64);
            a2 += __shfl_down(a2, off, 64);
        }
        if ((threadIdx.x & 63) == 0) {
            atomicAdd(&ssum[oc], a);
            atomicAdd(&ssq[oc],  a2);
        }
    }
    __syncthreads();
    if (threadIdx.x < OC) {
        atomicAdd(&sums[threadIdx.x],  ssum[threadIdx.x]);
        atomicAdd(&sumsq[threadIdx.x], ssq[threadIdx.x]);
    }
}

// recompute A2, BN + SiLU + residual, write fp32 out
__global__ void k_final(const float* __restrict__ vbuf,
                        const int* __restrict__ idx,
                        const float* __restrict__ W2g,
                        const float* __restrict__ b2g,
                        const float* __restrict__ x1,
                        const float* __restrict__ sums, const float* __restrict__ sumsq,
                        const float* __restrict__ gamma, const float* __restrict__ beta,
                        float* __restrict__ out) {
    int i = blockIdx.x, b = blockIdx.y;
    __shared__ float w2s[OC*OC];
    __shared__ float b2s[OC];
    __shared__ int   id[OC];
    __shared__ float mean_s[OC], inv_s[OC], g_s[OC], be_s[OC];
    for (int t = threadIdx.x; t < OC*OC; t += blockDim.x) w2s[t] = W2g[t];
    if (threadIdx.x < OC) {
        int oc = threadIdx.x;
        b2s[oc] = b2g[oc];
        id[oc]  = idx[(b*NHD + oc)*HH + i];
        const float N = (float)(NB*HH*WW);
        float mean = sums[oc]/N;
        float var  = sumsq[oc]/N - mean*mean;
        mean_s[oc] = mean;
        inv_s[oc]  = rsqrtf(var + 1e-5f);
        g_s[oc]    = gamma[oc];
        be_s[oc]   = beta[oc];
    }
    __syncthreads();
    int wv = threadIdx.x;
    if (wv >= WW) return;
    float vals[OC];
    for (int c = 0; c < OC; ++c)
        vals[c] = vbuf[((size_t)(b*OC + c)*HH + id[c])*WW + wv];
    for (int oc = 0; oc < OC; ++oc) {
        float a = b2s[oc];
        for (int c = 0; c < OC; ++c) a = fmaf(w2s[oc*OC + c], vals[c], a);
        float an = (a - mean_s[oc])*inv_s[oc]*g_s[oc] + be_s[oc];
        float sw = an / (1.f + __expf(-an));
        size_t o = ((size_t)(b*OC + oc)*HH + i)*WW + wv;
        out[o] = sw + x1[o];
    }
}

extern "C" void kernel_launch(void* const* d_in, const int* in_sizes, int n_in,
                              void* d_out, int out_size, void* d_ws, size_t ws_size,
                              hipStream_t stream) {
    const float* x      = (const float*)d_in[0];
    const float* gumbel = (const float*)d_in[1];
    const float* in_w   = (const float*)d_in[2];
    const float* in_b   = (const float*)d_in[3];
    const float* qkv_w  = (const float*)d_in[4];
    const float* proj_w = (const float*)d_in[5];
    const float* proj_b = (const float*)d_in[6];
    const float* upd_w  = (const float*)d_in[7];
    const float* upd_b  = (const float*)d_in[8];
    const float* bng    = (const float*)d_in[9];
    const float* bnb    = (const float*)d_in[10];

    float* out = (float*)d_out;
    float* att = out + (size_t)NB*OC*HWSZ;

    // ws layout, total ~116 MB
    float* x1   = (float*)d_ws;                      // 12,845,056 f (51.4 MB)
    float* qkb  = x1 + (size_t)NB*OC*HWSZ;           //  3,211,264 f (12.8 MB, per-batch)
    float* vbuf = qkb + (size_t)64*HWSZ;             // 12,845,056 f (51.4 MB)
    float* W2   = vbuf + (size_t)NB*OC*HWSZ;         // 1024
    float* b2   = W2 + OC*OC;                        // 32
    float* sums = b2 + OC;                           // 32
    float* sumsq= sums + OC;                         // 32
    int*   idx  = (int*)(sumsq + OC);                // 57,344 ints

    hipMemsetAsync(sums, 0, 2*OC*sizeof(float), stream);

    k_w2       <<<1, dim3(OC, OC), 0, stream>>>(proj_w, proj_b, upd_w, upd_b, W2, b2);
    k_conv_in32<<<dim3(HH, OC, NB), 256, 0, stream>>>(x, in_w, in_b, x1);

    for (int b = 0; b < NB; ++b) {
        k_conv_qkv_tile<<<dim3(HH/HT, C96/OCT), 256, 0, stream>>>(
            x1 + (size_t)b*OC*HWSZ, qkv_w, qkb, vbuf + (size_t)b*OC*HWSZ);
        k_attn_ri<<<dim3(HH/8, NHD), 256, 0, stream>>>(
            qkb,
            gumbel + (size_t)b*NH*HD*HH*HH,
            att    + (size_t)b*NH*HD*HH*HH,
            idx    + (size_t)b*NHD*HH);
    }

    k_gather_stats<<<dim3(HH, NB), 256, 0, stream>>>(vbuf, idx, W2, b2, sums, sumsq);
    k_final       <<<dim3(HH, NB), 256, 0, stream>>>(vbuf, idx, W2, b2, x1, sums, sumsq, bng, bnb, out);
}

// Round 10
// 994.350 us; speedup vs baseline: 4.3483x; 1.3860x over previous
//
#include <hip/hip_runtime.h>
#include <hip/hip_bf16.h>

#define NB 8
#define CIN 3
#define HH 224
#define WW 224
#define OC 32
#define NH 8
#define HD 4
#define NHD 32   // NH*HD
#define C96 96
#define HWSZ (HH*WW)

#define HT 4     // h rows per block (conv_qkv tile)
#define OCT 8    // output channels per block
#define NGB 4    // batches per group dispatch

// W2 = upd_w @ proj_w ; b2 = upd_w @ proj_b + upd_b   (1x1 conv composition)
__global__ void k_w2(const float* __restrict__ pw, const float* __restrict__ pb,
                     const float* __restrict__ uw, const float* __restrict__ ub,
                     float* __restrict__ W2, float* __restrict__ b2) {
    int c = threadIdx.x, o = threadIdx.y;  // 32x32
    float acc = 0.f;
    for (int m = 0; m < OC; ++m) acc = fmaf(uw[o*OC + m], pw[m*OC + c], acc);
    W2[o*OC + c] = acc;
    if (c == 0) {
        float bb = ub[o];
        for (int m = 0; m < OC; ++m) bb = fmaf(uw[o*OC + m], pb[m], bb);
        b2[o] = bb;
    }
}

// Tiled input conv: block = 2 h-rows x all 32 oc. Stage 3ch x 4 rows in LDS once.
// Per-output order frozen: c asc -> kh -> kw single fmaf chain, bias added after.
__global__ __launch_bounds__(256) void k_conv_in_tile(const float* __restrict__ x,
                                                      const float* __restrict__ w,
                                                      const float* __restrict__ bias,
                                                      float* __restrict__ x1) {
    int h0 = blockIdx.x * 2;
    int b  = blockIdx.y;
    __shared__ float xs[CIN][4][226];
    int t = threadIdx.x;
    for (int ch = 0; ch < CIN; ++ch)
        for (int r = 0; r < 4; ++r) {
            int gh = h0 - 1 + r;
            for (int col = t; col < 226; col += 256) {
                float v = 0.f;
                if (gh >= 0 && gh < HH && col > 0 && col < 225)
                    v = x[((size_t)(b*CIN + ch)*HH + gh)*WW + (col-1)];
                xs[ch][r][col] = v;
            }
        }
    __syncthreads();
    int wv = t;
    if (wv >= WW) return;
    float xv[CIN][4][3];
    #pragma unroll
    for (int c = 0; c < CIN; ++c)
        #pragma unroll
        for (int r = 0; r < 4; ++r)
            #pragma unroll
            for (int j = 0; j < 3; ++j)
                xv[c][r][j] = xs[c][r][wv + j];
    float acc[2][OC];
    #pragma unroll
    for (int hy = 0; hy < 2; ++hy)
        for (int oc = 0; oc < OC; ++oc) acc[hy][oc] = 0.f;
    #pragma unroll
    for (int c = 0; c < CIN; ++c)
        #pragma unroll
        for (int kh = 0; kh < 3; ++kh)
            #pragma unroll
            for (int kw = 0; kw < 3; ++kw)
                for (int oc = 0; oc < OC; ++oc) {
                    float wgt = w[oc*CIN*9 + c*9 + kh*3 + kw];  // uniform -> s_load
                    #pragma unroll
                    for (int hy = 0; hy < 2; ++hy)
                        acc[hy][oc] = fmaf(xv[c][hy+kh][kw], wgt, acc[hy][oc]);
                }
    for (int oc = 0; oc < OC; ++oc) {
        float bs = bias[oc];
        #pragma unroll
        for (int hy = 0; hy < 2; ++hy)
            x1[((size_t)(b*OC + oc)*HH + (h0+hy))*WW + wv] = __fadd_rn(acc[hy][oc], bs);
    }
}

// Tiled qkv conv, double-buffered staging, NGB batches per dispatch (grid.z).
// Per-output accumulation order frozen: c asc -> kh -> kw, single fmaf chain.
__global__ __launch_bounds__(256) void k_conv_qkv_tile(const float* __restrict__ x1g,
                                                       const float* __restrict__ w,
                                                       float* __restrict__ qk4,
                                                       float* __restrict__ vbg) {
    int h0 = blockIdx.x * HT;          // 56 tiles
    int og = blockIdx.y * OCT;         // 12 groups
    int z  = blockIdx.z;               // local batch
    const float* x1b = x1g + (size_t)z*OC*HWSZ;
    float* qk = qk4 + (size_t)z*64*HWSZ;
    float* vb = vbg + (size_t)z*OC*HWSZ;
    __shared__ float xs[2][HT+2][226];
    int t = threadIdx.x;
    int wv = t;
    float acc[HT][OCT];
    #pragma unroll
    for (int a = 0; a < HT; ++a)
        #pragma unroll
        for (int o = 0; o < OCT; ++o) acc[a][o] = 0.f;

    // stage c=0 into buf 0
    for (int r = 0; r < HT+2; ++r) {
        int gh = h0 - 1 + r;
        for (int col = t; col < 226; col += 256) {
            float v = 0.f;
            if (gh >= 0 && gh < HH && col > 0 && col < 225)
                v = x1b[((size_t)0*HH + gh)*WW + (col-1)];
            xs[0][r][col] = v;
        }
    }
    __syncthreads();

    for (int c = 0; c < OC; ++c) {
        int cur = c & 1;
        if (c + 1 < OC) {                       // prefetch next channel into other buf
            int nxt = cur ^ 1;
            for (int r = 0; r < HT+2; ++r) {
                int gh = h0 - 1 + r;
                for (int col = t; col < 226; col += 256) {
                    float v = 0.f;
                    if (gh >= 0 && gh < HH && col > 0 && col < 225)
                        v = x1b[((size_t)(c+1)*HH + gh)*WW + (col-1)];
                    xs[nxt][r][col] = v;
                }
            }
        }
        if (wv < WW) {
            float xv[HT+2][3];
            #pragma unroll
            for (int r = 0; r < HT+2; ++r)
                #pragma unroll
                for (int j = 0; j < 3; ++j)
                    xv[r][j] = xs[cur][r][wv + j];
            #pragma unroll
            for (int o = 0; o < OCT; ++o) {
                const float* wr = w + ((size_t)(og + o)*OC + c)*9;
                #pragma unroll
                for (int kh = 0; kh < 3; ++kh)
                    #pragma unroll
                    for (int kw = 0; kw < 3; ++kw) {
                        float wgt = wr[kh*3 + kw];
                        #pragma unroll
                        for (int hy = 0; hy < HT; ++hy)
                            acc[hy][o] = fmaf(xv[hy+kh][kw], wgt, acc[hy][o]);
                    }
            }
        }
        __syncthreads();
    }
    if (wv < WW) {
        #pragma unroll
        for (int o = 0; o < OCT; ++o) {
            int oc = og + o;
            int n = oc / 12, rem = oc % 12;
            int r = rem >> 2, d = rem & 3;
            #pragma unroll
            for (int hy = 0; hy < HT; ++hy) {
                int h = h0 + hy;
                if (r < 2)
                    qk[((size_t)(n*8 + r*4 + d)*HH + h)*WW + wv] = acc[hy][o];
                else
                    vb[((size_t)(n*4 + d)*HH + h)*WW + wv] = acc[hy][o];
            }
        }
    }
}

// attention: block = (16 i-rows, nd, z). Thread groups of 128: sub g=t>>7 owns rows
// g*8..g*8+7; s=t&127 (<112) owns j in {s, s+112} (k-rows in regs; q broadcast LDS).
// Dot semantics frozen (np.einsum SSE1: 4 no-fma lanes asc w, (s0+s1)+(s2+s3);
// 0.5f* exact; gumbel added last). Argmax: ascending-j strict >, ties to smaller j.
__global__ __launch_bounds__(256) void k_attn_rj(const float* __restrict__ qk4,
                                                 const float* __restrict__ gumg,
                                                 float* __restrict__ attg,
                                                 int* __restrict__ idxg) {
    int i0 = blockIdx.x * 16;
    int nd = blockIdx.y;
    int z  = blockIdx.z;
    int n = nd >> 2, d = nd & 3;
    const float* qk = qk4 + (size_t)z*64*HWSZ;
    const float* gum = gumg + (size_t)z*NH*HD*HH*HH;
    float* att = attg + (size_t)z*NH*HD*HH*HH;
    int* idxout = idxg + (size_t)z*NHD*HH;
    const float* qb = qk + ((size_t)(n*8 + d)*HH + i0)*WW;
    const float* kb = qk + ((size_t)(n*8 + 4 + d)*HH)*WW;
    __shared__ __align__(16) float qs[16][WW];
    __shared__ float vals[16][256];
    __shared__ int   win_s[16];
    int t = threadIdx.x;
    for (int f = t; f < 16*(WW/4); f += 256) {        // 896 float4
        int r = f / 56, p = (f % 56)*4;
        *(float4*)(&qs[r][p]) = *(const float4*)(qb + (size_t)r*WW + p);
    }
    for (int e = t; e < 16*32; e += 256) {            // pad j in [224,256) with -INF
        int r = e >> 5, cc = 224 + (e & 31);
        vals[r][cc] = -INFINITY;
    }
    __syncthreads();
    int g = t >> 7, s = t & 127;
    if (s < 112) {
        int j0 = s, j1 = s + 112;
        const float* kr0 = kb + (size_t)j0*WW;
        const float* kr1 = kb + (size_t)j1*WW;
        float s0[8][2], s1[8][2], s2[8][2], s3[8][2];
        #pragma unroll
        for (int r = 0; r < 8; ++r)
            #pragma unroll
            for (int jj = 0; jj < 2; ++jj) { s0[r][jj]=0.f; s1[r][jj]=0.f; s2[r][jj]=0.f; s3[r][jj]=0.f; }
        for (int w = 0; w < WW; w += 4) {
            float4 kc0 = *(const float4*)(kr0 + w);
            float4 kc1 = *(const float4*)(kr1 + w);
            #pragma unroll
            for (int r = 0; r < 8; ++r) {
                float4 qc = *(const float4*)(&qs[g*8 + r][w]);
                s0[r][0] = __fadd_rn(s0[r][0], __fmul_rn(qc.x, kc0.x));
                s1[r][0] = __fadd_rn(s1[r][0], __fmul_rn(qc.y, kc0.y));
                s2[r][0] = __fadd_rn(s2[r][0], __fmul_rn(qc.z, kc0.z));
                s3[r][0] = __fadd_rn(s3[r][0], __fmul_rn(qc.w, kc0.w));
                s0[r][1] = __fadd_rn(s0[r][1], __fmul_rn(qc.x, kc1.x));
                s1[r][1] = __fadd_rn(s1[r][1], __fmul_rn(qc.y, kc1.y));
                s2[r][1] = __fadd_rn(s2[r][1], __fmul_rn(qc.z, kc1.z));
                s3[r][1] = __fadd_rn(s3[r][1], __fmul_rn(qc.w, kc1.w));
            }
        }
        #pragma unroll
        for (int r = 0; r < 8; ++r) {
            int i = i0 + g*8 + r;
            float dot0 = __fadd_rn(__fadd_rn(s0[r][0], s1[r][0]), __fadd_rn(s2[r][0], s3[r][0]));
            float dot1 = __fadd_rn(__fadd_rn(s0[r][1], s1[r][1]), __fadd_rn(s2[r][1], s3[r][1]));
            vals[g*8 + r][j0] = __fadd_rn(__fmul_rn(0.5f, dot0), gum[((size_t)nd*HH + i)*HH + j0]);
            vals[g*8 + r][j1] = __fadd_rn(__fmul_rn(0.5f, dot1), gum[((size_t)nd*HH + i)*HH + j1]);
        }
    }
    __syncthreads();
    int ii = t >> 4, jj = t & 15;
    float best = -INFINITY; int bj = 0x7fffffff;
    for (int j = jj; j < 256; j += 16) {              // ascending: strict > keeps first
        float v = vals[ii][j];
        if (v > best) { best = v; bj = j; }
    }
    #pragma unroll
    for (int off = 8; off > 0; off >>= 1) {
        float v2 = __shfl_down(best, off, 16);
        int   j2 = __shfl_down(bj,   off, 16);
        if (v2 > best || (v2 == best && j2 < bj)) { best = v2; bj = j2; }
    }
    if (jj == 0) { win_s[ii] = bj; idxout[nd*HH + i0 + ii] = bj; }
    __syncthreads();
    for (int e = t; e < 16*WW; e += 256) {
        int r = e / WW, j = e - r*WW;
        att[((size_t)nd*HH + (i0 + r))*HH + j] = (j == win_s[r]) ? 1.f : 0.f;
    }
}

// recompute A2 = W2*gather(v) + b2 per pixel, accumulate per-channel sum/sumsq
__global__ void k_gather_stats(const float* __restrict__ vbuf,
                               const int* __restrict__ idx,
                               const float* __restrict__ W2g,
                               const float* __restrict__ b2g,
                               float* __restrict__ sums, float* __restrict__ sumsq) {
    int i = blockIdx.x, b = blockIdx.y;
    __shared__ float w2s[OC*OC];
    __shared__ float b2s[OC];
    __shared__ int   id[OC];
    __shared__ float ssum[OC], ssq[OC];
    for (int t = threadIdx.x; t < OC*OC; t += blockDim.x) w2s[t] = W2g[t];
    if (threadIdx.x < OC) {
        b2s[threadIdx.x]  = b2g[threadIdx.x];
        id[threadIdx.x]   = idx[(b*NHD + threadIdx.x)*HH + i];
        ssum[threadIdx.x] = 0.f;
        ssq[threadIdx.x]  = 0.f;
    }
    __syncthreads();
    int wv = threadIdx.x;
    bool act = wv < WW;
    float vals[OC];
    if (act)
        for (int c = 0; c < OC; ++c)
            vals[c] = vbuf[((size_t)(b*OC + c)*HH + id[c])*WW + wv];
    for (int oc = 0; oc < OC; ++oc) {
        float a = 0.f, a2 = 0.f;
        if (act) {
            a = b2s[oc];
            for (int c = 0; c < OC; ++c) a = fmaf(w2s[oc*OC + c], vals[c], a);
            a2 = a*a;
        }
        for (int off = 32; off > 0; off >>= 1) {
            a  += __shfl_down(a,  off, 64);
            a2 += __shfl_down(a2, off, 64);
        }
        if ((threadIdx.x & 63) == 0) {
            atomicAdd(&ssum[oc], a);
            atomicAdd(&ssq[oc],  a2);
        }
    }
    __syncthreads();
    if (threadIdx.x < OC) {
        atomicAdd(&sums[threadIdx.x],  ssum[threadIdx.x]);
        atomicAdd(&sumsq[threadIdx.x], ssq[threadIdx.x]);
    }
}

// recompute A2, BN + SiLU + residual, write fp32 out
__global__ void k_final(const float* __restrict__ vbuf,
                        const int* __restrict__ idx,
                        const float* __restrict__ W2g,
                        const float* __restrict__ b2g,
                        const float* __restrict__ x1,
                        const float* __restrict__ sums, const float* __restrict__ sumsq,
                        const float* __restrict__ gamma, const float* __restrict__ beta,
                        float* __restrict__ out) {
    int i = blockIdx.x, b = blockIdx.y;
    __shared__ float w2s[OC*OC];
    __shared__ float b2s[OC];
    __shared__ int   id[OC];
    __shared__ float mean_s[OC], inv_s[OC], g_s[OC], be_s[OC];
    for (int t = threadIdx.x; t < OC*OC; t += blockDim.x) w2s[t] = W2g[t];
    if (threadIdx.x < OC) {
        int oc = threadIdx.x;
        b2s[oc] = b2g[oc];
        id[oc]  = idx[(b*NHD + oc)*HH + i];
        const float N = (float)(NB*HH*WW);
        float mean = sums[oc]/N;
        float var  = sumsq[oc]/N - mean*mean;
        mean_s[oc] = mean;
        inv_s[oc]  = rsqrtf(var + 1e-5f);
        g_s[oc]    = gamma[oc];
        be_s[oc]   = beta[oc];
    }
    __syncthreads();
    int wv = threadIdx.x;
    if (wv >= WW) return;
    float vals[OC];
    for (int c = 0; c < OC; ++c)
        vals[c] = vbuf[((size_t)(b*OC + c)*HH + id[c])*WW + wv];
    for (int oc = 0; oc < OC; ++oc) {
        float a = b2s[oc];
        for (int c = 0; c < OC; ++c) a = fmaf(w2s[oc*OC + c], vals[c], a);
        float an = (a - mean_s[oc])*inv_s[oc]*g_s[oc] + be_s[oc];
        float sw = an / (1.f + __expf(-an));
        size_t o = ((size_t)(b*OC + oc)*HH + i)*WW + wv;
        out[o] = sw + x1[o];
    }
}

extern "C" void kernel_launch(void* const* d_in, const int* in_sizes, int n_in,
                              void* d_out, int out_size, void* d_ws, size_t ws_size,
                              hipStream_t stream) {
    const float* x      = (const float*)d_in[0];
    const float* gumbel = (const float*)d_in[1];
    const float* in_w   = (const float*)d_in[2];
    const float* in_b   = (const float*)d_in[3];
    const float* qkv_w  = (const float*)d_in[4];
    const float* proj_w = (const float*)d_in[5];
    const float* proj_b = (const float*)d_in[6];
    const float* upd_w  = (const float*)d_in[7];
    const float* upd_b  = (const float*)d_in[8];
    const float* bng    = (const float*)d_in[9];
    const float* bnb    = (const float*)d_in[10];

    float* out = (float*)d_out;
    float* att = out + (size_t)NB*OC*HWSZ;

    // ws layout, total ~154.3 MB
    float* x1   = (float*)d_ws;                      // 12,845,056 f (51.4 MB)
    float* qk4  = x1 + (size_t)NB*OC*HWSZ;           // 12,845,056 f (51.4 MB, 4 batches)
    float* vbuf = qk4 + (size_t)NGB*64*HWSZ;         // 12,845,056 f (51.4 MB)
    float* W2   = vbuf + (size_t)NB*OC*HWSZ;         // 1024
    float* b2   = W2 + OC*OC;                        // 32
    float* sums = b2 + OC;                           // 32
    float* sumsq= sums + OC;                         // 32
    int*   idx  = (int*)(sumsq + OC);                // 57,344 ints

    hipMemsetAsync(sums, 0, 2*OC*sizeof(float), stream);

    k_w2          <<<1, dim3(OC, OC), 0, stream>>>(proj_w, proj_b, upd_w, upd_b, W2, b2);
    k_conv_in_tile<<<dim3(HH/2, NB), 256, 0, stream>>>(x, in_w, in_b, x1);

    for (int g = 0; g < NB/NGB; ++g) {
        k_conv_qkv_tile<<<dim3(HH/HT, C96/OCT, NGB), 256, 0, stream>>>(
            x1 + (size_t)g*NGB*OC*HWSZ, qkv_w, qk4, vbuf + (size_t)g*NGB*OC*HWSZ);
        k_attn_rj<<<dim3(HH/16, NHD, NGB), 256, 0, stream>>>(
            qk4,
            gumbel + (size_t)g*NGB*NH*HD*HH*HH,
            att    + (size_t)g*NGB*NH*HD*HH*HH,
            idx    + (size_t)g*NGB*NHD*HH);
    }

    k_gather_stats<<<dim3(HH, NB), 256, 0, stream>>>(vbuf, idx, W2, b2, sums, sumsq);
    k_final       <<<dim3(HH, NB), 256, 0, stream>>>(vbuf, idx, W2, b2, x1, sums, sumsq, bng, bnb, out);
}

// Round 11
// 879.076 us; speedup vs baseline: 4.9185x; 1.1311x over previous
//
#include <hip/hip_runtime.h>
#include <hip/hip_bf16.h>

#define NB 8
#define CIN 3
#define HH 224
#define WW 224
#define OC 32
#define NH 8
#define HD 4
#define NHD 32   // NH*HD
#define C96 96
#define HWSZ (HH*WW)

#define HT 4     // h rows per block (conv_qkv tile)
#define OCT 8    // output channels per block
#define NGB 4    // batches per qkv group dispatch

// W2 = upd_w @ proj_w ; b2 = upd_w @ proj_b + upd_b   (1x1 conv composition)
__global__ void k_w2(const float* __restrict__ pw, const float* __restrict__ pb,
                     const float* __restrict__ uw, const float* __restrict__ ub,
                     float* __restrict__ W2, float* __restrict__ b2) {
    int c = threadIdx.x, o = threadIdx.y;  // 32x32
    float acc = 0.f;
    for (int m = 0; m < OC; ++m) acc = fmaf(uw[o*OC + m], pw[m*OC + c], acc);
    W2[o*OC + c] = acc;
    if (c == 0) {
        float bb = ub[o];
        for (int m = 0; m < OC; ++m) bb = fmaf(uw[o*OC + m], pb[m], bb);
        b2[o] = bb;
    }
}

// Tiled input conv: block = 2 h-rows x all 32 oc. Stage 3ch x 4 rows in LDS once.
// Per-output order frozen: c asc -> kh -> kw single fmaf chain, bias added after.
__global__ __launch_bounds__(256) void k_conv_in_tile(const float* __restrict__ x,
                                                      const float* __restrict__ w,
                                                      const float* __restrict__ bias,
                                                      float* __restrict__ x1) {
    int h0 = blockIdx.x * 2;
    int b  = blockIdx.y;
    __shared__ float xs[CIN][4][226];
    int t = threadIdx.x;
    for (int ch = 0; ch < CIN; ++ch)
        for (int r = 0; r < 4; ++r) {
            int gh = h0 - 1 + r;
            for (int col = t; col < 226; col += 256) {
                float v = 0.f;
                if (gh >= 0 && gh < HH && col > 0 && col < 225)
                    v = x[((size_t)(b*CIN + ch)*HH + gh)*WW + (col-1)];
                xs[ch][r][col] = v;
            }
        }
    __syncthreads();
    int wv = t;
    if (wv >= WW) return;
    float xv[CIN][4][3];
    #pragma unroll
    for (int c = 0; c < CIN; ++c)
        #pragma unroll
        for (int r = 0; r < 4; ++r)
            #pragma unroll
            for (int j = 0; j < 3; ++j)
                xv[c][r][j] = xs[c][r][wv + j];
    float acc[2][OC];
    #pragma unroll
    for (int hy = 0; hy < 2; ++hy)
        for (int oc = 0; oc < OC; ++oc) acc[hy][oc] = 0.f;
    #pragma unroll
    for (int c = 0; c < CIN; ++c)
        #pragma unroll
        for (int kh = 0; kh < 3; ++kh)
            #pragma unroll
            for (int kw = 0; kw < 3; ++kw)
                for (int oc = 0; oc < OC; ++oc) {
                    float wgt = w[oc*CIN*9 + c*9 + kh*3 + kw];  // uniform -> s_load
                    #pragma unroll
                    for (int hy = 0; hy < 2; ++hy)
                        acc[hy][oc] = fmaf(xv[c][hy+kh][kw], wgt, acc[hy][oc]);
                }
    for (int oc = 0; oc < OC; ++oc) {
        float bs = bias[oc];
        #pragma unroll
        for (int hy = 0; hy < 2; ++hy)
            x1[((size_t)(b*OC + oc)*HH + (h0+hy))*WW + wv] = __fadd_rn(acc[hy][oc], bs);
    }
}

// Tiled qkv conv, double-buffered staging, NGB batches per dispatch (grid.z).
// Per-output accumulation order frozen: c asc -> kh -> kw, single fmaf chain.
__global__ __launch_bounds__(256) void k_conv_qkv_tile(const float* __restrict__ x1g,
                                                       const float* __restrict__ w,
                                                       float* __restrict__ qk4,
                                                       float* __restrict__ vbg) {
    int h0 = blockIdx.x * HT;          // 56 tiles
    int og = blockIdx.y * OCT;         // 12 groups
    int z  = blockIdx.z;               // local batch
    const float* x1b = x1g + (size_t)z*OC*HWSZ;
    float* qk = qk4 + (size_t)z*64*HWSZ;
    float* vb = vbg + (size_t)z*OC*HWSZ;
    __shared__ float xs[2][HT+2][226];
    int t = threadIdx.x;
    int wv = t;
    float acc[HT][OCT];
    #pragma unroll
    for (int a = 0; a < HT; ++a)
        #pragma unroll
        for (int o = 0; o < OCT; ++o) acc[a][o] = 0.f;

    // stage c=0 into buf 0
    for (int r = 0; r < HT+2; ++r) {
        int gh = h0 - 1 + r;
        for (int col = t; col < 226; col += 256) {
            float v = 0.f;
            if (gh >= 0 && gh < HH && col > 0 && col < 225)
                v = x1b[((size_t)0*HH + gh)*WW + (col-1)];
            xs[0][r][col] = v;
        }
    }
    __syncthreads();

    for (int c = 0; c < OC; ++c) {
        int cur = c & 1;
        if (c + 1 < OC) {                       // prefetch next channel into other buf
            int nxt = cur ^ 1;
            for (int r = 0; r < HT+2; ++r) {
                int gh = h0 - 1 + r;
                for (int col = t; col < 226; col += 256) {
                    float v = 0.f;
                    if (gh >= 0 && gh < HH && col > 0 && col < 225)
                        v = x1b[((size_t)(c+1)*HH + gh)*WW + (col-1)];
                    xs[nxt][r][col] = v;
                }
            }
        }
        if (wv < WW) {
            float xv[HT+2][3];
            #pragma unroll
            for (int r = 0; r < HT+2; ++r)
                #pragma unroll
                for (int j = 0; j < 3; ++j)
                    xv[r][j] = xs[cur][r][wv + j];
            #pragma unroll
            for (int o = 0; o < OCT; ++o) {
                const float* wr = w + ((size_t)(og + o)*OC + c)*9;
                #pragma unroll
                for (int kh = 0; kh < 3; ++kh)
                    #pragma unroll
                    for (int kw = 0; kw < 3; ++kw) {
                        float wgt = wr[kh*3 + kw];
                        #pragma unroll
                        for (int hy = 0; hy < HT; ++hy)
                            acc[hy][o] = fmaf(xv[hy+kh][kw], wgt, acc[hy][o]);
                    }
            }
        }
        __syncthreads();
    }
    if (wv < WW) {
        #pragma unroll
        for (int o = 0; o < OCT; ++o) {
            int oc = og + o;
            int n = oc / 12, rem = oc % 12;
            int r = rem >> 2, d = rem & 3;
            #pragma unroll
            for (int hy = 0; hy < HT; ++hy) {
                int h = h0 + hy;
                if (r < 2)
                    qk[((size_t)(n*8 + r*4 + d)*HH + h)*WW + wv] = acc[hy][o];
                else
                    vb[((size_t)(n*4 + d)*HH + h)*WW + wv] = acc[hy][o];
            }
        }
    }
}

// attention (r9-proven): block = (8 i-rows, nd), per-batch dispatch. Thread t owns
// j=t, computes dots for all 8 i-rows (k-row float4, q broadcast from LDS).
// Dot semantics frozen: np.einsum SSE1 — 4 separate no-fma lanes over ascending w,
// reduce (s0+s1)+(s2+s3); 0.5f* exact; gumbel added last. Argmax: strict >, first j.
__global__ __launch_bounds__(256) void k_attn_ri(const float* __restrict__ qk,
                                                 const float* __restrict__ gum,
                                                 float* __restrict__ att,
                                                 int* __restrict__ idxout) {
    int i0 = blockIdx.x * 8;
    int nd = blockIdx.y;
    int n = nd >> 2, d = nd & 3;
    const float* qb = qk + ((size_t)(n*8 + d)*HH + i0)*WW;
    const float* kb = qk + ((size_t)(n*8 + 4 + d)*HH)*WW;
    __shared__ __align__(16) float qs[8][WW];
    __shared__ float vals[8][256];
    __shared__ int   win_s[8];
    int t = threadIdx.x;
    for (int f = t; f < 8*(WW/4); f += 256) {         // 448 float4
        int r = f / (WW/4), p = (f % (WW/4))*4;
        *(float4*)(&qs[r][p]) = *(const float4*)(qb + (size_t)r*WW + p);
    }
    __syncthreads();
    if (t < WW) {
        const float* kr = kb + (size_t)t*WW;
        float s0[8], s1[8], s2[8], s3[8];
        #pragma unroll
        for (int ii = 0; ii < 8; ++ii) { s0[ii]=0.f; s1[ii]=0.f; s2[ii]=0.f; s3[ii]=0.f; }
        for (int w = 0; w < WW; w += 4) {
            float4 kc = *(const float4*)(kr + w);
            #pragma unroll
            for (int ii = 0; ii < 8; ++ii) {
                float4 qc = *(const float4*)(&qs[ii][w]);
                s0[ii] = __fadd_rn(s0[ii], __fmul_rn(qc.x, kc.x));
                s1[ii] = __fadd_rn(s1[ii], __fmul_rn(qc.y, kc.y));
                s2[ii] = __fadd_rn(s2[ii], __fmul_rn(qc.z, kc.z));
                s3[ii] = __fadd_rn(s3[ii], __fmul_rn(qc.w, kc.w));
            }
        }
        #pragma unroll
        for (int ii = 0; ii < 8; ++ii) {
            float dot = __fadd_rn(__fadd_rn(s0[ii], s1[ii]), __fadd_rn(s2[ii], s3[ii]));
            vals[ii][t] = __fadd_rn(__fmul_rn(0.5f, dot),
                                    gum[((size_t)nd*HH + (i0 + ii))*HH + t]);
        }
    } else {
        #pragma unroll
        for (int ii = 0; ii < 8; ++ii) vals[ii][t] = -INFINITY;
    }
    __syncthreads();
    int ii = t >> 5, jj = t & 31;
    float best = -INFINITY; int bj = 0x7fffffff;
    for (int j = jj; j < 256; j += 32) {              // ascending j: strict > keeps first
        float v = vals[ii][j];
        if (v > best) { best = v; bj = j; }
    }
    for (int off = 16; off > 0; off >>= 1) {
        float v2 = __shfl_down(best, off, 32);
        int   j2 = __shfl_down(bj,   off, 32);
        if (v2 > best || (v2 == best && j2 < bj)) { best = v2; bj = j2; }
    }
    if (jj == 0) { win_s[ii] = bj; idxout[nd*HH + i0 + ii] = bj; }
    __syncthreads();
    for (int e = t; e < 8*WW; e += 256) {
        int r = e / WW, j = e - r*WW;
        att[((size_t)nd*HH + (i0 + r))*HH + j] = (j == win_s[r]) ? 1.f : 0.f;
    }
}

// A2 = W2*gather(v) + b2 per pixel — gather + 32x32 mm done ONCE, A2 written out.
__global__ void k_gather_mm(const float* __restrict__ vbuf,
                            const int* __restrict__ idx,
                            const float* __restrict__ W2g,
                            const float* __restrict__ b2g,
                            float* __restrict__ A2) {
    int i = blockIdx.x, b = blockIdx.y;
    __shared__ float w2s[OC*OC];
    __shared__ float b2s[OC];
    __shared__ int   id[OC];
    for (int t = threadIdx.x; t < OC*OC; t += blockDim.x) w2s[t] = W2g[t];
    if (threadIdx.x < OC) {
        b2s[threadIdx.x] = b2g[threadIdx.x];
        id[threadIdx.x]  = idx[(b*NHD + threadIdx.x)*HH + i];
    }
    __syncthreads();
    int wv = threadIdx.x;
    if (wv >= WW) return;
    float vals[OC];
    for (int c = 0; c < OC; ++c)
        vals[c] = vbuf[((size_t)(b*OC + c)*HH + id[c])*WW + wv];
    for (int oc = 0; oc < OC; ++oc) {
        float a = b2s[oc];
        for (int c = 0; c < OC; ++c) a = fmaf(w2s[oc*OC + c], vals[c], a);
        A2[((size_t)(b*OC + oc)*HH + i)*WW + wv] = a;
    }
}

// linear float4 reduction over A2 for per-channel sum/sumsq
__global__ __launch_bounds__(256) void k_stats(const float* __restrict__ A2,
                                               float* __restrict__ sums,
                                               float* __restrict__ sumsq) {
    int oc = blockIdx.x, s = blockIdx.y;    // 16 slabs
    int t = threadIdx.x;
    float a = 0.f, a2 = 0.f;
    const int SL = HWSZ/16;                 // 3136
    for (int b = 0; b < NB; ++b) {
        const float* base = A2 + (size_t)(b*OC + oc)*HWSZ + s*SL;
        for (int e = t*4; e < SL; e += 256*4) {
            float4 v = *(const float4*)(base + e);
            a  += v.x + v.y + v.z + v.w;
            a2 += v.x*v.x + v.y*v.y + v.z*v.z + v.w*v.w;
        }
    }
    __shared__ float r1[256], r2[256];
    r1[t] = a; r2[t] = a2;
    __syncthreads();
    for (int st = 128; st > 0; st >>= 1) {
        if (t < st) { r1[t] += r1[t+st]; r2[t] += r2[t+st]; }
        __syncthreads();
    }
    if (t == 0) { atomicAdd(&sums[oc], r1[0]); atomicAdd(&sumsq[oc], r2[0]); }
}

// streaming BN + SiLU + residual from A2, write fp32 out
__global__ __launch_bounds__(256) void k_final(const float* __restrict__ A2,
                                               const float* __restrict__ x1,
                                               const float* __restrict__ sums,
                                               const float* __restrict__ sumsq,
                                               const float* __restrict__ gamma,
                                               const float* __restrict__ beta,
                                               float* __restrict__ out) {
    int i = blockIdx.x, b = blockIdx.y;
    __shared__ float mean_s[OC], inv_s[OC], g_s[OC], be_s[OC];
    if (threadIdx.x < OC) {
        int oc = threadIdx.x;
        const float N = (float)(NB*HH*WW);
        float mean = sums[oc]/N;
        float var  = sumsq[oc]/N - mean*mean;
        mean_s[oc] = mean;
        inv_s[oc]  = rsqrtf(var + 1e-5f);
        g_s[oc]    = gamma[oc];
        be_s[oc]   = beta[oc];
    }
    __syncthreads();
    int wv = threadIdx.x;
    if (wv >= WW) return;
    for (int oc = 0; oc < OC; ++oc) {
        size_t o = ((size_t)(b*OC + oc)*HH + i)*WW + wv;
        float a = A2[o];
        float an = (a - mean_s[oc])*inv_s[oc]*g_s[oc] + be_s[oc];
        float sw = an / (1.f + __expf(-an));
        out[o] = sw + x1[o];
    }
}

extern "C" void kernel_launch(void* const* d_in, const int* in_sizes, int n_in,
                              void* d_out, int out_size, void* d_ws, size_t ws_size,
                              hipStream_t stream) {
    const float* x      = (const float*)d_in[0];
    const float* gumbel = (const float*)d_in[1];
    const float* in_w   = (const float*)d_in[2];
    const float* in_b   = (const float*)d_in[3];
    const float* qkv_w  = (const float*)d_in[4];
    const float* proj_w = (const float*)d_in[5];
    const float* proj_b = (const float*)d_in[6];
    const float* upd_w  = (const float*)d_in[7];
    const float* upd_b  = (const float*)d_in[8];
    const float* bng    = (const float*)d_in[9];
    const float* bnb    = (const float*)d_in[10];

    float* out = (float*)d_out;
    float* att = out + (size_t)NB*OC*HWSZ;

    // ws layout, total ~154.3 MB. A2 aliases qk4 (both 12,845,056 f) — qk dead after attn.
    float* x1   = (float*)d_ws;                      // 12,845,056 f (51.4 MB)
    float* qk4  = x1 + (size_t)NB*OC*HWSZ;           // 12,845,056 f (51.4 MB, 4 batches)
    float* A2   = qk4;                               // alias
    float* vbuf = qk4 + (size_t)NGB*64*HWSZ;         // 12,845,056 f (51.4 MB)
    float* W2   = vbuf + (size_t)NB*OC*HWSZ;         // 1024
    float* b2   = W2 + OC*OC;                        // 32
    float* sums = b2 + OC;                           // 32
    float* sumsq= sums + OC;                         // 32
    int*   idx  = (int*)(sumsq + OC);                // 57,344 ints

    hipMemsetAsync(sums, 0, 2*OC*sizeof(float), stream);

    k_w2          <<<1, dim3(OC, OC), 0, stream>>>(proj_w, proj_b, upd_w, upd_b, W2, b2);
    k_conv_in_tile<<<dim3(HH/2, NB), 256, 0, stream>>>(x, in_w, in_b, x1);

    for (int g = 0; g < NB/NGB; ++g) {
        k_conv_qkv_tile<<<dim3(HH/HT, C96/OCT, NGB), 256, 0, stream>>>(
            x1 + (size_t)g*NGB*OC*HWSZ, qkv_w, qk4, vbuf + (size_t)g*NGB*OC*HWSZ);
        for (int z = 0; z < NGB; ++z) {
            int b = g*NGB + z;
            k_attn_ri<<<dim3(HH/8, NHD), 256, 0, stream>>>(
                qk4    + (size_t)z*64*HWSZ,
                gumbel + (size_t)b*NH*HD*HH*HH,
                att    + (size_t)b*NH*HD*HH*HH,
                idx    + (size_t)b*NHD*HH);
        }
    }

    k_gather_mm<<<dim3(HH, NB), 256, 0, stream>>>(vbuf, idx, W2, b2, A2);
    k_stats    <<<dim3(OC, 16), 256, 0, stream>>>(A2, sums, sumsq);
    k_final    <<<dim3(HH, NB), 256, 0, stream>>>(A2, x1, sums, sumsq, bng, bnb, out);
}